// Round 1
// baseline (302.888 us; speedup 1.0000x reference)
//
#include <hip/hip_runtime.h>
#include <hip/hip_bf16.h>

#define N_EXPERTS 32
#define K_SEL 4
#define IN_C 1024
#define OUT_C 1024
#define BATCH 4096
#define NTOK (BATCH * K_SEL)   // 16384

#define BM 128
#define BN 128
#define BKK 32
#define LDK 40                  // padded LDS leading dim (bf16 elems): 80B rows, 16B-aligned
#define MAX_TILES (N_EXPERTS + NTOK / BM)   // 160 worst case

// ws layout (ints)
#define WS_COUNTS 0
#define WS_CURSOR 32
#define WS_NTILES 64
#define WS_TABLE 128                       // 4 ints per tile
#define WS_ROWLIST (WS_TABLE + MAX_TILES * 4)  // 768

typedef __attribute__((ext_vector_type(4))) float f32x4;
typedef __attribute__((ext_vector_type(8))) short bf16x8;

__device__ __forceinline__ unsigned short f2bf(float f) {
    union { float f; unsigned u; } v; v.f = f;
    unsigned r = v.u + 0x7fffu + ((v.u >> 16) & 1u);   // RNE
    return (unsigned short)(r >> 16);
}

__global__ void count_kernel(const int* __restrict__ idx, int* __restrict__ ws) {
    int s = blockIdx.x * blockDim.x + threadIdx.x;
    if (s < NTOK) {
        int e = idx[s] & (N_EXPERTS - 1);
        atomicAdd(&ws[WS_COUNTS + e], 1);
    }
}

__global__ void scan_kernel(int* __restrict__ ws) {
    if (threadIdx.x != 0) return;
    int off = 0, tiles = 0;
    for (int e = 0; e < N_EXPERTS; ++e) {
        int c = ws[WS_COUNTS + e];
        ws[WS_CURSOR + e] = off;                 // scatter cursor starts at segment base
        for (int t = 0; t < c; t += BM) {
            ws[WS_TABLE + tiles * 4 + 0] = e;
            ws[WS_TABLE + tiles * 4 + 1] = off + t;
            ws[WS_TABLE + tiles * 4 + 2] = (c - t) < BM ? (c - t) : BM;
            ws[WS_TABLE + tiles * 4 + 3] = 0;
            ++tiles;
        }
        off += c;
    }
    ws[WS_NTILES] = tiles;
}

__global__ void scatter_kernel(const int* __restrict__ idx, int* __restrict__ ws) {
    int s = blockIdx.x * blockDim.x + threadIdx.x;
    if (s < NTOK) {
        int e = idx[s] & (N_EXPERTS - 1);
        int p = atomicAdd(&ws[WS_CURSOR + e], 1);
        ws[WS_ROWLIST + p] = s;
    }
}

__global__ __launch_bounds__(256, 2)
void gemm_kernel(const float* __restrict__ x, const float* __restrict__ w,
                 const float* __restrict__ bias, const int* __restrict__ ws,
                 float* __restrict__ out) {
    int ntiles = ws[WS_NTILES];
    if ((int)blockIdx.x >= ntiles) return;
    const int e     = ws[WS_TABLE + blockIdx.x * 4 + 0];
    const int list0 = ws[WS_TABLE + blockIdx.x * 4 + 1];
    const int nrows = ws[WS_TABLE + blockIdx.x * 4 + 2];
    const int n0 = blockIdx.y * BN;

    __shared__ unsigned short As[BM][LDK];   // tokens x k (bf16 bits)
    __shared__ unsigned short Bs[BN][LDK];   // TRANSPOSED: out-col x k
    __shared__ int rowtok[BM];

    const int t = threadIdx.x;
    if (t < BM) {
        int r = t < nrows - 1 ? t : nrows - 1;
        rowtok[t] = ws[WS_ROWLIST + list0 + r];
    }
    __syncthreads();

    // A staging: 2 threads per row, 16 cols each
    const int arow = t >> 1, acol0 = (t & 1) * 16;
    // B staging: 8 threads per k-row, 16 cols each
    const int brow = t >> 3, bcol0 = (t & 7) * 16;

    const float* xbase = x + (size_t)(rowtok[arow] >> 2) * IN_C + acol0;
    const float* wbase = w + (size_t)e * IN_C * OUT_C + (size_t)brow * OUT_C + n0 + bcol0;

    const int lane = t & 63, wid = t >> 6;
    const int wr = wid >> 1, wc = wid & 1;        // 2x2 wave grid, 64x64 each
    const int lrow = lane & 15, lq = lane >> 4;   // fragment lane decomposition

    f32x4 acc[4][4];
    #pragma unroll
    for (int m = 0; m < 4; ++m)
        #pragma unroll
        for (int n = 0; n < 4; ++n) acc[m][n] = (f32x4)0.f;

    for (int k0 = 0; k0 < IN_C; k0 += BKK) {
        __syncthreads();
        // stage A (f32 -> bf16)
        #pragma unroll
        for (int u = 0; u < 4; ++u) {
            f32x4 v = *(const f32x4*)(xbase + k0 + 4 * u);
            ushort4 pk;
            pk.x = f2bf(v.x); pk.y = f2bf(v.y); pk.z = f2bf(v.z); pk.w = f2bf(v.w);
            *(ushort4*)&As[arow][acol0 + 4 * u] = pk;
        }
        // stage B transposed
        #pragma unroll
        for (int u = 0; u < 4; ++u) {
            f32x4 v = *(const f32x4*)(wbase + (size_t)k0 * OUT_C + 4 * u);
            Bs[bcol0 + 4 * u + 0][brow] = f2bf(v.x);
            Bs[bcol0 + 4 * u + 1][brow] = f2bf(v.y);
            Bs[bcol0 + 4 * u + 2][brow] = f2bf(v.z);
            Bs[bcol0 + 4 * u + 3][brow] = f2bf(v.w);
        }
        __syncthreads();

        bf16x8 a[4], b[4];
        #pragma unroll
        for (int m = 0; m < 4; ++m)
            a[m] = *(const bf16x8*)&As[wr * 64 + m * 16 + lrow][lq * 8];
        #pragma unroll
        for (int n = 0; n < 4; ++n)
            b[n] = *(const bf16x8*)&Bs[wc * 64 + n * 16 + lrow][lq * 8];

        #pragma unroll
        for (int m = 0; m < 4; ++m)
            #pragma unroll
            for (int n = 0; n < 4; ++n)
                acc[m][n] = __builtin_amdgcn_mfma_f32_16x16x32_bf16(a[m], b[n], acc[m][n], 0, 0, 0);
    }

    // epilogue: C/D layout col = lane&15, row = (lane>>4)*4 + j  [verified m89/m91]
    #pragma unroll
    for (int m = 0; m < 4; ++m) {
        #pragma unroll
        for (int j = 0; j < 4; ++j) {
            int row = wr * 64 + m * 16 + lq * 4 + j;
            if (row < nrows) {
                int s = rowtok[row];
                float* orow = out + (size_t)s * OUT_C;
                #pragma unroll
                for (int n = 0; n < 4; ++n) {
                    int col = n0 + wc * 64 + n * 16 + lrow;
                    float vv = acc[m][n][j] + bias[e * OUT_C + col];
                    orow[col] = vv > 0.f ? vv : 0.f;
                }
            }
        }
    }
}

extern "C" void kernel_launch(void* const* d_in, const int* in_sizes, int n_in,
                              void* d_out, int out_size, void* d_ws, size_t ws_size,
                              hipStream_t stream) {
    const float* x    = (const float*)d_in[0];
    const int*   idx  = (const int*)d_in[1];
    const float* w    = (const float*)d_in[2];
    const float* bias = (const float*)d_in[3];
    float* out = (float*)d_out;
    int* ws = (int*)d_ws;

    hipMemsetAsync(ws, 0, (WS_TABLE + MAX_TILES * 4) * sizeof(int), stream);
    count_kernel<<<NTOK / 256, 256, 0, stream>>>(idx, ws);
    scan_kernel<<<1, 64, 0, stream>>>(ws);
    scatter_kernel<<<NTOK / 256, 256, 0, stream>>>(idx, ws);
    dim3 grid(MAX_TILES, OUT_C / BN);
    gemm_kernel<<<grid, 256, 0, stream>>>(x, w, bias, ws, out);
}

// Round 2
// 196.720 us; speedup vs baseline: 1.5397x; 1.5397x over previous
//
#include <hip/hip_runtime.h>
#include <hip/hip_bf16.h>

#define N_EXPERTS 32
#define K_SEL 4
#define IN_C 1024
#define OUT_C 1024
#define BATCH 4096
#define NTOK (BATCH * K_SEL)   // 16384

#define BM 128
#define BN 128
#define BK 64
#define MAX_TILES (N_EXPERTS + NTOK / BM)   // 160 worst case

// bf16 workspace layout (bytes)
#define WT_ELEMS (N_EXPERTS * IN_C * OUT_C)          // 33,554,432
#define XB_ELEMS (BATCH * IN_C)                      // 4,194,304
#define CTRL_OFF_BYTES ((size_t)WT_ELEMS * 2 + (size_t)XB_ELEMS * 2)

// control ints (relative to ctrl base)
#define WS_COUNTS 0
#define WS_CURSOR 32
#define WS_NTILES 64
#define WS_TABLE 128                        // 4 ints per tile
#define WS_ROWLIST (WS_TABLE + MAX_TILES * 4)
#define CTRL_INTS (WS_ROWLIST + NTOK)

typedef __attribute__((ext_vector_type(4))) float f32x4;
typedef __attribute__((ext_vector_type(8))) short bf16x8;
typedef __attribute__((ext_vector_type(8))) unsigned short u16x8;

__device__ __forceinline__ unsigned short f2bf(float f) {
    union { float f; unsigned u; } v; v.f = f;
    unsigned r = v.u + 0x7fffu + ((v.u >> 16) & 1u);   // RNE
    return (unsigned short)(r >> 16);
}

__device__ __forceinline__ void gload16(const void* g, void* l) {
    __builtin_amdgcn_global_load_lds(
        (const __attribute__((address_space(1))) unsigned int*)g,
        (__attribute__((address_space(3))) unsigned int*)l, 16, 0, 0);
}

// ---------------- prep kernels ----------------

__global__ void xconv_kernel(const float* __restrict__ x, unsigned short* __restrict__ xb) {
    int i = (blockIdx.x * 256 + threadIdx.x) << 3;
    f32x4 v0 = *(const f32x4*)(x + i);
    f32x4 v1 = *(const f32x4*)(x + i + 4);
    u16x8 o;
    o[0] = f2bf(v0.x); o[1] = f2bf(v0.y); o[2] = f2bf(v0.z); o[3] = f2bf(v0.w);
    o[4] = f2bf(v1.x); o[5] = f2bf(v1.y); o[6] = f2bf(v1.z); o[7] = f2bf(v1.w);
    *(u16x8*)(xb + i) = o;
}

// W[e][k][n] f32  ->  Wt[e][n][k] bf16, 64x64 LDS-tiled transpose
__global__ __launch_bounds__(256)
void wconv_kernel(const float* __restrict__ w, unsigned short* __restrict__ wt) {
    __shared__ float tb[64][65];
    const int e = blockIdx.x >> 8;
    const int tile = blockIdx.x & 255;
    const int kb = (tile >> 4) << 6;
    const int nb = (tile & 15) << 6;
    const float* src = w + (size_t)e * (IN_C * OUT_C);
    const int t = threadIdx.x;
    const int r = t >> 2, c0 = (t & 3) << 4;
    #pragma unroll
    for (int u = 0; u < 4; ++u) {
        f32x4 v = *(const f32x4*)(src + (size_t)(kb + r) * OUT_C + nb + c0 + (u << 2));
        tb[r][c0 + (u << 2) + 0] = v.x;
        tb[r][c0 + (u << 2) + 1] = v.y;
        tb[r][c0 + (u << 2) + 2] = v.z;
        tb[r][c0 + (u << 2) + 3] = v.w;
    }
    __syncthreads();
    unsigned short* dst = wt + (size_t)e * (IN_C * OUT_C) + (size_t)(nb + r) * IN_C + kb + c0;
    u16x8 o0, o1;
    #pragma unroll
    for (int j = 0; j < 8; ++j) o0[j] = f2bf(tb[c0 + j][r]);
    #pragma unroll
    for (int j = 0; j < 8; ++j) o1[j] = f2bf(tb[c0 + 8 + j][r]);
    *(u16x8*)dst = o0;
    *(u16x8*)(dst + 8) = o1;
}

// ---------------- bucketing ----------------

__global__ void count_kernel(const int* __restrict__ idx, int* __restrict__ ctrl) {
    int s = blockIdx.x * blockDim.x + threadIdx.x;
    if (s < NTOK) {
        int e = idx[s] & (N_EXPERTS - 1);
        atomicAdd(&ctrl[WS_COUNTS + e], 1);
    }
}

__global__ void scan_kernel(int* __restrict__ ctrl) {
    if (threadIdx.x != 0) return;
    int off = 0, tiles = 0;
    for (int e = 0; e < N_EXPERTS; ++e) {
        int c = ctrl[WS_COUNTS + e];
        ctrl[WS_CURSOR + e] = off;
        for (int t = 0; t < c; t += BM) {
            ctrl[WS_TABLE + tiles * 4 + 0] = e;
            ctrl[WS_TABLE + tiles * 4 + 1] = off + t;
            ctrl[WS_TABLE + tiles * 4 + 2] = (c - t) < BM ? (c - t) : BM;
            ctrl[WS_TABLE + tiles * 4 + 3] = 0;
            ++tiles;
        }
        off += c;
    }
    ctrl[WS_NTILES] = tiles;
}

__global__ void scatter_kernel(const int* __restrict__ idx, int* __restrict__ ctrl) {
    int s = blockIdx.x * blockDim.x + threadIdx.x;
    if (s < NTOK) {
        int e = idx[s] & (N_EXPERTS - 1);
        int p = atomicAdd(&ctrl[WS_CURSOR + e], 1);
        ctrl[WS_ROWLIST + p] = s;
    }
}

// ---------------- bf16 grouped GEMM (m97 structure + src-swizzle) ----------------

__global__ __launch_bounds__(256, 3)
void gemm_kernel(const unsigned short* __restrict__ xb,
                 const unsigned short* __restrict__ wt,
                 const float* __restrict__ bias,
                 const int* __restrict__ ctrl,
                 float* __restrict__ out) {
    const int ntiles = ctrl[WS_NTILES];
    if ((int)blockIdx.x >= ntiles) return;
    const int e     = ctrl[WS_TABLE + blockIdx.x * 4 + 0];
    const int list0 = ctrl[WS_TABLE + blockIdx.x * 4 + 1];
    const int nrows = ctrl[WS_TABLE + blockIdx.x * 4 + 2];
    const int n0 = blockIdx.y * BN;

    __shared__ unsigned short As[BM][BK];   // linear; content chunk-swizzled via source perm
    __shared__ unsigned short Bs[BN][BK];   // Wt rows (n-major), same swizzle
    __shared__ int rowtok[BM];

    const int t = threadIdx.x;
    const int lane = t & 63, w = t >> 6;

    if (t < BM) {
        int r = t < nrows ? t : nrows - 1;
        rowtok[t] = ctrl[WS_ROWLIST + list0 + r];
    }
    __syncthreads();

    // staging: wave w covers rows [w*32, w*32+32), 4 insts x (8 rows x 8 chunks)
    // LDS dest is linear (base + lane*16). Source chunk is pre-swizzled so that
    // LDS[row][c'] holds global chunk c = c' ^ (row&7).
    const int cg = (lane & 7) ^ (lane >> 3);     // global 16B-chunk this lane fetches
    const unsigned short* asrc[4];
    const unsigned short* bsrc[4];
    #pragma unroll
    for (int i = 0; i < 4; ++i) {
        int row = (w << 5) + (i << 3) + (lane >> 3);
        asrc[i] = xb + (size_t)(rowtok[row] >> 2) * IN_C + (cg << 3);
        bsrc[i] = wt + (size_t)e * (IN_C * OUT_C) + (size_t)(n0 + row) * IN_C + (cg << 3);
    }

    const int wr = (t >> 7) & 1;          // 2x2 wave grid, 64x64 per wave
    const int wc = (t >> 6) & 1;
    const int lrow = lane & 15, lq = lane >> 4;
    // fragment read: chunk' = (kk*4+lq) ^ (row&7); row&7 == lrow&7
    const int fo0 = ((lq) ^ (lrow & 7)) << 4;       // kk=0 byte offset in row
    const int fo1 = ((4 + lq) ^ (lrow & 7)) << 4;   // kk=1
    const char* aB = (const char*)&As[wr * 64 + lrow][0];
    const char* bB = (const char*)&Bs[wc * 64 + lrow][0];

    f32x4 acc[4][4];
    #pragma unroll
    for (int m = 0; m < 4; ++m)
        #pragma unroll
        for (int n = 0; n < 4; ++n) acc[m][n] = (f32x4)0.f;

    for (int k0 = 0; k0 < IN_C; k0 += BK) {
        __syncthreads();                       // prior ds_reads done before overwrite
        #pragma unroll
        for (int i = 0; i < 4; ++i) {
            gload16(asrc[i] + k0, &As[(w << 5) + (i << 3)][0]);
            gload16(bsrc[i] + k0, &Bs[(w << 5) + (i << 3)][0]);
        }
        __syncthreads();                       // compiler drains vmcnt(0) before barrier

        #pragma unroll
        for (int kk = 0; kk < 2; ++kk) {
            const int fo = kk ? fo1 : fo0;
            bf16x8 a[4], b[4];
            #pragma unroll
            for (int m = 0; m < 4; ++m) a[m] = *(const bf16x8*)(aB + m * 2048 + fo);
            #pragma unroll
            for (int n = 0; n < 4; ++n) b[n] = *(const bf16x8*)(bB + n * 2048 + fo);
            #pragma unroll
            for (int m = 0; m < 4; ++m)
                #pragma unroll
                for (int n = 0; n < 4; ++n)
                    acc[m][n] = __builtin_amdgcn_mfma_f32_16x16x32_bf16(a[m], b[n], acc[m][n], 0, 0, 0);
        }
    }

    // C/D layout: col = lane&15, row = (lane>>4)*4 + j   [verified m89/m91]
    #pragma unroll
    for (int m = 0; m < 4; ++m) {
        #pragma unroll
        for (int j = 0; j < 4; ++j) {
            int row = wr * 64 + m * 16 + lq * 4 + j;
            if (row < nrows) {
                int s = rowtok[row];
                float* orow = out + (size_t)s * OUT_C;
                #pragma unroll
                for (int n = 0; n < 4; ++n) {
                    int col = n0 + wc * 64 + n * 16 + lrow;
                    float vv = acc[m][n][j] + bias[e * OUT_C + col];
                    orow[col] = vv > 0.f ? vv : 0.f;
                }
            }
        }
    }
}

// ---------------- fallback f32 GEMM (round-1 proven) for small ws ----------------

__global__ __launch_bounds__(256, 2)
void gemm_f32_kernel(const float* __restrict__ x, const float* __restrict__ w,
                     const float* __restrict__ bias, const int* __restrict__ ctrl,
                     float* __restrict__ out) {
    int ntiles = ctrl[WS_NTILES];
    if ((int)blockIdx.x >= ntiles) return;
    const int e     = ctrl[WS_TABLE + blockIdx.x * 4 + 0];
    const int list0 = ctrl[WS_TABLE + blockIdx.x * 4 + 1];
    const int nrows = ctrl[WS_TABLE + blockIdx.x * 4 + 2];
    const int n0 = blockIdx.y * BN;

    __shared__ unsigned short As2[BM][40];
    __shared__ unsigned short Bs2[BN][40];
    __shared__ int rowtok[BM];

    const int t = threadIdx.x;
    if (t < BM) {
        int r = t < nrows ? t : nrows - 1;
        rowtok[t] = ctrl[WS_ROWLIST + list0 + r];
    }
    __syncthreads();

    const int arow = t >> 1, acol0 = (t & 1) * 16;
    const int brow = t >> 3, bcol0 = (t & 7) * 16;
    const float* xbase = x + (size_t)(rowtok[arow] >> 2) * IN_C + acol0;
    const float* wbase = w + (size_t)e * IN_C * OUT_C + (size_t)brow * OUT_C + n0 + bcol0;

    const int lane = t & 63, wid = t >> 6;
    const int wr = wid >> 1, wc = wid & 1;
    const int lrow = lane & 15, lq = lane >> 4;

    f32x4 acc[4][4];
    #pragma unroll
    for (int m = 0; m < 4; ++m)
        #pragma unroll
        for (int n = 0; n < 4; ++n) acc[m][n] = (f32x4)0.f;

    for (int k0 = 0; k0 < IN_C; k0 += 32) {
        __syncthreads();
        #pragma unroll
        for (int u = 0; u < 4; ++u) {
            f32x4 v = *(const f32x4*)(xbase + k0 + 4 * u);
            ushort4 pk;
            pk.x = f2bf(v.x); pk.y = f2bf(v.y); pk.z = f2bf(v.z); pk.w = f2bf(v.w);
            *(ushort4*)&As2[arow][acol0 + 4 * u] = pk;
        }
        #pragma unroll
        for (int u = 0; u < 4; ++u) {
            f32x4 v = *(const f32x4*)(wbase + (size_t)k0 * OUT_C + 4 * u);
            Bs2[bcol0 + 4 * u + 0][brow] = f2bf(v.x);
            Bs2[bcol0 + 4 * u + 1][brow] = f2bf(v.y);
            Bs2[bcol0 + 4 * u + 2][brow] = f2bf(v.z);
            Bs2[bcol0 + 4 * u + 3][brow] = f2bf(v.w);
        }
        __syncthreads();

        bf16x8 a[4], b[4];
        #pragma unroll
        for (int m = 0; m < 4; ++m) a[m] = *(const bf16x8*)&As2[wr * 64 + m * 16 + lrow][lq * 8];
        #pragma unroll
        for (int n = 0; n < 4; ++n) b[n] = *(const bf16x8*)&Bs2[wc * 64 + n * 16 + lrow][lq * 8];
        #pragma unroll
        for (int m = 0; m < 4; ++m)
            #pragma unroll
            for (int n = 0; n < 4; ++n)
                acc[m][n] = __builtin_amdgcn_mfma_f32_16x16x32_bf16(a[m], b[n], acc[m][n], 0, 0, 0);
    }

    #pragma unroll
    for (int m = 0; m < 4; ++m) {
        #pragma unroll
        for (int j = 0; j < 4; ++j) {
            int row = wr * 64 + m * 16 + lq * 4 + j;
            if (row < nrows) {
                int s = rowtok[row];
                float* orow = out + (size_t)s * OUT_C;
                #pragma unroll
                for (int n = 0; n < 4; ++n) {
                    int col = n0 + wc * 64 + n * 16 + lrow;
                    float vv = acc[m][n][j] + bias[e * OUT_C + col];
                    orow[col] = vv > 0.f ? vv : 0.f;
                }
            }
        }
    }
}

// ---------------- launch ----------------

extern "C" void kernel_launch(void* const* d_in, const int* in_sizes, int n_in,
                              void* d_out, int out_size, void* d_ws, size_t ws_size,
                              hipStream_t stream) {
    const float* x    = (const float*)d_in[0];
    const int*   idx  = (const int*)d_in[1];
    const float* w    = (const float*)d_in[2];
    const float* bias = (const float*)d_in[3];
    float* out = (float*)d_out;

    const size_t need = CTRL_OFF_BYTES + (size_t)CTRL_INTS * sizeof(int);
    if (ws_size >= need) {
        unsigned short* wt = (unsigned short*)d_ws;
        unsigned short* xb = (unsigned short*)((char*)d_ws + (size_t)WT_ELEMS * 2);
        int* ctrl = (int*)((char*)d_ws + CTRL_OFF_BYTES);

        hipMemsetAsync(ctrl, 0, 512, stream);
        xconv_kernel<<<XB_ELEMS / 2048, 256, 0, stream>>>(x, xb);
        wconv_kernel<<<N_EXPERTS * 256, 256, 0, stream>>>(w, wt);
        count_kernel<<<NTOK / 256, 256, 0, stream>>>(idx, ctrl);
        scan_kernel<<<1, 64, 0, stream>>>(ctrl);
        scatter_kernel<<<NTOK / 256, 256, 0, stream>>>(idx, ctrl);
        dim3 grid(MAX_TILES, OUT_C / BN);
        gemm_kernel<<<grid, 256, 0, stream>>>(xb, wt, bias, ctrl, out);
    } else {
        int* ctrl = (int*)d_ws;
        hipMemsetAsync(ctrl, 0, 512, stream);
        count_kernel<<<NTOK / 256, 256, 0, stream>>>(idx, ctrl);
        scan_kernel<<<1, 64, 0, stream>>>(ctrl);
        scatter_kernel<<<NTOK / 256, 256, 0, stream>>>(idx, ctrl);
        dim3 grid(MAX_TILES, OUT_C / BN);
        gemm_f32_kernel<<<grid, 256, 0, stream>>>(x, w, bias, ctrl, out);
    }
}

// Round 3
// 119.510 us; speedup vs baseline: 2.5344x; 1.6461x over previous
//
#include <hip/hip_runtime.h>
#include <hip/hip_bf16.h>

#define N_EXPERTS 32
#define K_SEL 4
#define IN_C 1024
#define OUT_C 1024
#define BATCH 4096
#define NTOK (BATCH * K_SEL)   // 16384

#define BM 128
#define BN 128
#define BK 64
#define MAX_TILES (N_EXPERTS + NTOK / BM)   // 160 worst case

// bf16 workspace layout (bytes)
#define WT_ELEMS (N_EXPERTS * IN_C * OUT_C)          // 33,554,432
#define XB_ELEMS (BATCH * IN_C)                      // 4,194,304
#define CTRL_OFF_BYTES ((size_t)WT_ELEMS * 2 + (size_t)XB_ELEMS * 2)

// control ints (relative to ctrl base)
#define WS_NTILES 0
#define WS_TABLE 8                          // 4 ints per tile
#define WS_ROWLIST (WS_TABLE + MAX_TILES * 4)
#define CTRL_INTS (WS_ROWLIST + NTOK)
// fallback layout additions
#define WS_COUNTS (CTRL_INTS)
#define WS_CURSOR (CTRL_INTS + 32)

typedef __attribute__((ext_vector_type(4))) float f32x4;
typedef __attribute__((ext_vector_type(8))) short bf16x8;
typedef __attribute__((ext_vector_type(8))) unsigned short u16x8;

__device__ __forceinline__ unsigned short f2bf(float f) {
    union { float f; unsigned u; } v; v.f = f;
    unsigned r = v.u + 0x7fffu + ((v.u >> 16) & 1u);   // RNE
    return (unsigned short)(r >> 16);
}

__device__ __forceinline__ void gload16(const void* g, void* l) {
    __builtin_amdgcn_global_load_lds(
        (const __attribute__((address_space(1))) unsigned int*)g,
        (__attribute__((address_space(3))) unsigned int*)l, 16, 0, 0);
}

// ---------------- fused prep: bucket (bid 0) + xconv + wconv ----------------

#define XCONV_B0 1
#define XCONV_NB (XB_ELEMS / 2048)          // 2048
#define WCONV_B0 (XCONV_B0 + XCONV_NB)      // 2049
#define WCONV_NB (N_EXPERTS * 256)          // 8192
#define PREP_NWG (WCONV_B0 + WCONV_NB)      // 10241

__global__ __launch_bounds__(256)
void prep_kernel(const float* __restrict__ x, const float* __restrict__ w,
                 const int* __restrict__ idx,
                 unsigned short* __restrict__ xb, unsigned short* __restrict__ wt,
                 int* __restrict__ ctrl) {
    const int bid = blockIdx.x;
    const int t = threadIdx.x;

    if (bid >= WCONV_B0) {
        // ---- W[e][k][n] f32 -> Wt[e][n][k] bf16, 64x64 LDS-tiled transpose ----
        __shared__ float tb[64][65];
        const int b = bid - WCONV_B0;
        const int e = b >> 8;
        const int tile = b & 255;
        const int kb = (tile >> 4) << 6;
        const int nb = (tile & 15) << 6;
        const float* src = w + (size_t)e * (IN_C * OUT_C);
        const int r = t >> 2, c0 = (t & 3) << 4;
        #pragma unroll
        for (int u = 0; u < 4; ++u) {
            f32x4 v = *(const f32x4*)(src + (size_t)(kb + r) * OUT_C + nb + c0 + (u << 2));
            tb[r][c0 + (u << 2) + 0] = v.x;
            tb[r][c0 + (u << 2) + 1] = v.y;
            tb[r][c0 + (u << 2) + 2] = v.z;
            tb[r][c0 + (u << 2) + 3] = v.w;
        }
        __syncthreads();
        unsigned short* dst = wt + (size_t)e * (IN_C * OUT_C) + (size_t)(nb + r) * IN_C + kb + c0;
        u16x8 o0, o1;
        #pragma unroll
        for (int j = 0; j < 8; ++j) o0[j] = f2bf(tb[c0 + j][r]);
        #pragma unroll
        for (int j = 0; j < 8; ++j) o1[j] = f2bf(tb[c0 + 8 + j][r]);
        *(u16x8*)dst = o0;
        *(u16x8*)(dst + 8) = o1;
    } else if (bid >= XCONV_B0) {
        // ---- x f32 -> bf16 ----
        int i = ((bid - XCONV_B0) * 256 + t) << 3;
        f32x4 v0 = *(const f32x4*)(x + i);
        f32x4 v1 = *(const f32x4*)(x + i + 4);
        u16x8 o;
        o[0] = f2bf(v0.x); o[1] = f2bf(v0.y); o[2] = f2bf(v0.z); o[3] = f2bf(v0.w);
        o[4] = f2bf(v1.x); o[5] = f2bf(v1.y); o[6] = f2bf(v1.z); o[7] = f2bf(v1.w);
        *(u16x8*)(xb + i) = o;
    } else {
        // ---- bucketing: count -> scan -> table -> scatter, one block ----
        __shared__ int cnt[N_EXPERTS], base[N_EXPERTS], tbase[N_EXPERTS];
        if (t < N_EXPERTS) cnt[t] = 0;
        __syncthreads();
        #pragma unroll 4
        for (int i = 0; i < NTOK / 256; ++i) {
            int e = idx[i * 256 + t] & (N_EXPERTS - 1);
            atomicAdd(&cnt[e], 1);
        }
        __syncthreads();
        if (t == 0) {
            int off = 0, tiles = 0;
            for (int e = 0; e < N_EXPERTS; ++e) {
                base[e] = off;
                tbase[e] = tiles;
                int c = cnt[e];
                tiles += (c + BM - 1) / BM;
                off += c;
            }
            ctrl[WS_NTILES] = tiles;
        }
        __syncthreads();
        if (t < N_EXPERTS) {
            int c = cnt[t], off = base[t], tt = tbase[t];
            for (int u = 0; u < c; u += BM, ++tt) {
                ctrl[WS_TABLE + tt * 4 + 0] = t;
                ctrl[WS_TABLE + tt * 4 + 1] = off + u;
                ctrl[WS_TABLE + tt * 4 + 2] = (c - u) < BM ? (c - u) : BM;
            }
            cnt[t] = off;   // becomes scatter cursor
        }
        __syncthreads();
        #pragma unroll 4
        for (int i = 0; i < NTOK / 256; ++i) {
            int s = i * 256 + t;
            int e = idx[s] & (N_EXPERTS - 1);
            int p = atomicAdd(&cnt[e], 1);
            ctrl[WS_ROWLIST + p] = s;
        }
    }
}

// ---------------- bf16 grouped GEMM (m97 structure + src-swizzle + XCD swizzle) ----

__global__ __launch_bounds__(256, 3)
void gemm_kernel(const unsigned short* __restrict__ xb,
                 const unsigned short* __restrict__ wt,
                 const float* __restrict__ bias,
                 const int* __restrict__ ctrl,
                 float* __restrict__ out) {
    // expert-clustered XCD swizzle: XCD j owns tiles [20j, 20j+20), nb-fastest
    const int swz = ((int)blockIdx.x & 7) * ((MAX_TILES * 8) >> 3) + ((int)blockIdx.x >> 3);
    const int tileIdx = swz >> 3;
    const int ntiles = ctrl[WS_NTILES];
    if (tileIdx >= ntiles) return;
    const int e     = ctrl[WS_TABLE + tileIdx * 4 + 0];
    const int list0 = ctrl[WS_TABLE + tileIdx * 4 + 1];
    const int nrows = ctrl[WS_TABLE + tileIdx * 4 + 2];
    const int n0 = (swz & 7) * BN;

    __shared__ unsigned short As[BM][BK];   // linear; content chunk-swizzled via source perm
    __shared__ unsigned short Bs[BN][BK];   // Wt rows (n-major), same swizzle
    __shared__ int rowtok[BM];

    const int t = threadIdx.x;
    const int lane = t & 63, w = t >> 6;

    if (t < BM) {
        int r = t < nrows ? t : nrows - 1;
        rowtok[t] = ctrl[WS_ROWLIST + list0 + r];
    }
    __syncthreads();

    // staging: wave w covers rows [w*32, w*32+32), 4 insts x (8 rows x 8 chunks)
    // LDS dest linear (base + lane*16); source chunk pre-swizzled so LDS[row][c']
    // holds global chunk c = c' ^ (row&7).
    const int cg = (lane & 7) ^ (lane >> 3);
    const unsigned short* asrc[4];
    const unsigned short* bsrc[4];
    #pragma unroll
    for (int i = 0; i < 4; ++i) {
        int row = (w << 5) + (i << 3) + (lane >> 3);
        asrc[i] = xb + (size_t)(rowtok[row] >> 2) * IN_C + (cg << 3);
        bsrc[i] = wt + (size_t)e * (IN_C * OUT_C) + (size_t)(n0 + row) * IN_C + (cg << 3);
    }

    const int wr = (t >> 7) & 1;          // 2x2 wave grid, 64x64 per wave
    const int wc = (t >> 6) & 1;
    const int lrow = lane & 15, lq = lane >> 4;
    const int fo0 = ((lq) ^ (lrow & 7)) << 4;       // kk=0 byte offset in row
    const int fo1 = ((4 + lq) ^ (lrow & 7)) << 4;   // kk=1
    const char* aB = (const char*)&As[wr * 64 + lrow][0];
    const char* bB = (const char*)&Bs[wc * 64 + lrow][0];

    f32x4 acc[4][4];
    #pragma unroll
    for (int m = 0; m < 4; ++m)
        #pragma unroll
        for (int n = 0; n < 4; ++n) acc[m][n] = (f32x4)0.f;

    for (int k0 = 0; k0 < IN_C; k0 += BK) {
        __syncthreads();
        #pragma unroll
        for (int i = 0; i < 4; ++i) {
            gload16(asrc[i] + k0, &As[(w << 5) + (i << 3)][0]);
            gload16(bsrc[i] + k0, &Bs[(w << 5) + (i << 3)][0]);
        }
        __syncthreads();

        #pragma unroll
        for (int kk = 0; kk < 2; ++kk) {
            const int fo = kk ? fo1 : fo0;
            bf16x8 a[4], b[4];
            #pragma unroll
            for (int m = 0; m < 4; ++m) a[m] = *(const bf16x8*)(aB + m * 2048 + fo);
            #pragma unroll
            for (int n = 0; n < 4; ++n) b[n] = *(const bf16x8*)(bB + n * 2048 + fo);
            #pragma unroll
            for (int m = 0; m < 4; ++m)
                #pragma unroll
                for (int n = 0; n < 4; ++n)
                    acc[m][n] = __builtin_amdgcn_mfma_f32_16x16x32_bf16(a[m], b[n], acc[m][n], 0, 0, 0);
        }
    }

    // C/D layout: col = lane&15, row = (lane>>4)*4 + j   [verified m89/m91]
    #pragma unroll
    for (int m = 0; m < 4; ++m) {
        #pragma unroll
        for (int j = 0; j < 4; ++j) {
            int row = wr * 64 + m * 16 + lq * 4 + j;
            if (row < nrows) {
                int s = rowtok[row];
                float* orow = out + (size_t)s * OUT_C;
                #pragma unroll
                for (int n = 0; n < 4; ++n) {
                    int col = n0 + wc * 64 + n * 16 + lrow;
                    float vv = acc[m][n][j] + bias[e * OUT_C + col];
                    orow[col] = vv > 0.f ? vv : 0.f;
                }
            }
        }
    }
}

// ---------------- fallback f32 path (round-1 proven) for small ws ----------------

__global__ void count_kernel(const int* __restrict__ idx, int* __restrict__ ctrl) {
    int s = blockIdx.x * blockDim.x + threadIdx.x;
    if (s < NTOK) atomicAdd(&ctrl[WS_COUNTS + (idx[s] & (N_EXPERTS - 1))], 1);
}

__global__ void scan_kernel(int* __restrict__ ctrl) {
    if (threadIdx.x != 0) return;
    int off = 0, tiles = 0;
    for (int e = 0; e < N_EXPERTS; ++e) {
        int c = ctrl[WS_COUNTS + e];
        ctrl[WS_CURSOR + e] = off;
        for (int t = 0; t < c; t += BM) {
            ctrl[WS_TABLE + tiles * 4 + 0] = e;
            ctrl[WS_TABLE + tiles * 4 + 1] = off + t;
            ctrl[WS_TABLE + tiles * 4 + 2] = (c - t) < BM ? (c - t) : BM;
            ++tiles;
        }
        off += c;
    }
    ctrl[WS_NTILES] = tiles;
}

__global__ void scatter_kernel(const int* __restrict__ idx, int* __restrict__ ctrl) {
    int s = blockIdx.x * blockDim.x + threadIdx.x;
    if (s < NTOK) {
        int e = idx[s] & (N_EXPERTS - 1);
        int p = atomicAdd(&ctrl[WS_CURSOR + e], 1);
        ctrl[WS_ROWLIST + p] = s;
    }
}

__global__ __launch_bounds__(256, 2)
void gemm_f32_kernel(const float* __restrict__ x, const float* __restrict__ w,
                     const float* __restrict__ bias, const int* __restrict__ ctrl,
                     float* __restrict__ out) {
    int ntiles = ctrl[WS_NTILES];
    if ((int)blockIdx.x >= ntiles) return;
    const int e     = ctrl[WS_TABLE + blockIdx.x * 4 + 0];
    const int list0 = ctrl[WS_TABLE + blockIdx.x * 4 + 1];
    const int nrows = ctrl[WS_TABLE + blockIdx.x * 4 + 2];
    const int n0 = blockIdx.y * BN;

    __shared__ unsigned short As2[BM][40];
    __shared__ unsigned short Bs2[BN][40];
    __shared__ int rowtok[BM];

    const int t = threadIdx.x;
    if (t < BM) {
        int r = t < nrows ? t : nrows - 1;
        rowtok[t] = ctrl[WS_ROWLIST + list0 + r];
    }
    __syncthreads();

    const int arow = t >> 1, acol0 = (t & 1) * 16;
    const int brow = t >> 3, bcol0 = (t & 7) * 16;
    const float* xbase = x + (size_t)(rowtok[arow] >> 2) * IN_C + acol0;
    const float* wbase = w + (size_t)e * IN_C * OUT_C + (size_t)brow * OUT_C + n0 + bcol0;

    const int lane = t & 63, wid = t >> 6;
    const int wr = wid >> 1, wc = wid & 1;
    const int lrow = lane & 15, lq = lane >> 4;

    f32x4 acc[4][4];
    #pragma unroll
    for (int m = 0; m < 4; ++m)
        #pragma unroll
        for (int n = 0; n < 4; ++n) acc[m][n] = (f32x4)0.f;

    for (int k0 = 0; k0 < IN_C; k0 += 32) {
        __syncthreads();
        #pragma unroll
        for (int u = 0; u < 4; ++u) {
            f32x4 v = *(const f32x4*)(xbase + k0 + 4 * u);
            ushort4 pk;
            pk.x = f2bf(v.x); pk.y = f2bf(v.y); pk.z = f2bf(v.z); pk.w = f2bf(v.w);
            *(ushort4*)&As2[arow][acol0 + 4 * u] = pk;
        }
        #pragma unroll
        for (int u = 0; u < 4; ++u) {
            f32x4 v = *(const f32x4*)(wbase + (size_t)k0 * OUT_C + 4 * u);
            Bs2[bcol0 + 4 * u + 0][brow] = f2bf(v.x);
            Bs2[bcol0 + 4 * u + 1][brow] = f2bf(v.y);
            Bs2[bcol0 + 4 * u + 2][brow] = f2bf(v.z);
            Bs2[bcol0 + 4 * u + 3][brow] = f2bf(v.w);
        }
        __syncthreads();

        bf16x8 a[4], b[4];
        #pragma unroll
        for (int m = 0; m < 4; ++m) a[m] = *(const bf16x8*)&As2[wr * 64 + m * 16 + lrow][lq * 8];
        #pragma unroll
        for (int n = 0; n < 4; ++n) b[n] = *(const bf16x8*)&Bs2[wc * 64 + n * 16 + lrow][lq * 8];
        #pragma unroll
        for (int m = 0; m < 4; ++m)
            #pragma unroll
            for (int n = 0; n < 4; ++n)
                acc[m][n] = __builtin_amdgcn_mfma_f32_16x16x32_bf16(a[m], b[n], acc[m][n], 0, 0, 0);
    }

    #pragma unroll
    for (int m = 0; m < 4; ++m) {
        #pragma unroll
        for (int j = 0; j < 4; ++j) {
            int row = wr * 64 + m * 16 + lq * 4 + j;
            if (row < nrows) {
                int s = rowtok[row];
                float* orow = out + (size_t)s * OUT_C;
                #pragma unroll
                for (int n = 0; n < 4; ++n) {
                    int col = n0 + wc * 64 + n * 16 + lrow;
                    float vv = acc[m][n][j] + bias[e * OUT_C + col];
                    orow[col] = vv > 0.f ? vv : 0.f;
                }
            }
        }
    }
}

// ---------------- launch ----------------

extern "C" void kernel_launch(void* const* d_in, const int* in_sizes, int n_in,
                              void* d_out, int out_size, void* d_ws, size_t ws_size,
                              hipStream_t stream) {
    const float* x    = (const float*)d_in[0];
    const int*   idx  = (const int*)d_in[1];
    const float* w    = (const float*)d_in[2];
    const float* bias = (const float*)d_in[3];
    float* out = (float*)d_out;

    const size_t need = CTRL_OFF_BYTES + (size_t)(CTRL_INTS + 64) * sizeof(int);
    if (ws_size >= need) {
        unsigned short* wt = (unsigned short*)d_ws;
        unsigned short* xb = (unsigned short*)((char*)d_ws + (size_t)WT_ELEMS * 2);
        int* ctrl = (int*)((char*)d_ws + CTRL_OFF_BYTES);

        prep_kernel<<<PREP_NWG, 256, 0, stream>>>(x, w, idx, xb, wt, ctrl);
        gemm_kernel<<<MAX_TILES * 8, 256, 0, stream>>>(xb, wt, bias, ctrl, out);
    } else {
        int* ctrl = (int*)d_ws;
        hipMemsetAsync(ctrl, 0, (CTRL_INTS + 64) * sizeof(int), stream);
        count_kernel<<<NTOK / 256, 256, 0, stream>>>(idx, ctrl);
        scan_kernel<<<1, 64, 0, stream>>>(ctrl);
        scatter_kernel<<<NTOK / 256, 256, 0, stream>>>(idx, ctrl);
        dim3 grid(MAX_TILES, OUT_C / BN);
        gemm_f32_kernel<<<grid, 256, 0, stream>>>(x, w, bias, ctrl, out);
    }
}